// Round 7
// baseline (2371.016 us; speedup 1.0000x reference)
//
#include <hip/hip_runtime.h>
#include <stdint.h>

#define BATCH  1024
#define SEQLEN 15
#define NGATE  2048
#define NVOCAB 11998
#define FEATS  4096

typedef __attribute__((ext_vector_type(8)))  short  s8v;     // 8 bf16 bit patterns
typedef __attribute__((ext_vector_type(16))) float  f32x16;  // 32x32 MFMA acc
typedef __attribute__((ext_vector_type(8)))  unsigned short us8;

__device__ __forceinline__ unsigned short f2bf(float f) {
    unsigned u = __float_as_uint(f);
    u += 0x7FFFu + ((u >> 16) & 1u);
    return (unsigned short)(u >> 16);
}
__device__ __forceinline__ float bf2f(unsigned short h) {
    return __uint_as_float(((unsigned)h) << 16);
}
struct bfpair { unsigned short hi, lo; };
__device__ __forceinline__ bfpair split2v(float v) {
    bfpair r;
    r.hi = f2bf(v);
    r.lo = f2bf(v - bf2f(r.hi));
    return r;
}
__device__ __forceinline__ void split8(const float* __restrict__ s, us8& vh, us8& vl) {
    #pragma unroll
    for (int e = 0; e < 8; ++e) {
        bfpair q = split2v(s[e]);
        vh[e] = q.hi; vl[e] = q.lo;
    }
}

// ---------------------------------------------------------------------------
// prep: Wcat blocked [128 kc][2048 row][8] = split([W_ih | W_hh]); bsum
// ---------------------------------------------------------------------------
__global__ void prep_wcat_blk(const float* __restrict__ W_ih, const float* __restrict__ W_hh,
                              const float* __restrict__ b_ih, const float* __restrict__ b_hh,
                              unsigned short* __restrict__ hi, unsigned short* __restrict__ lo,
                              float* __restrict__ bsum) {
    int idx = blockIdx.x * 256 + threadIdx.x;   // 128*2048
    int kc = idx >> 11, row = idx & 2047;
    int k = kc << 3;
    const float* src = (k < 512) ? (W_ih + (size_t)row * 512 + k)
                                 : (W_hh + (size_t)row * 512 + (k - 512));
    us8 vh, vl; split8(src, vh, vl);
    *(us8*)(hi + (size_t)idx * 8) = vh;
    *(us8*)(lo + (size_t)idx * 8) = vl;
    if (idx < NGATE) bsum[idx] = b_ih[idx] + b_hh[idx];
}

// src [R][K] fp32 -> hi/lo [K/8][R][8] bf16. grid: (ceil(R/256), K/8)
__global__ void prep_blk(const float* __restrict__ src,
                         unsigned short* __restrict__ hi, unsigned short* __restrict__ lo,
                         int R, int K) {
    int row = blockIdx.x * 256 + threadIdx.x;
    if (row >= R) return;
    int kc = blockIdx.y;
    us8 vh, vl; split8(src + (size_t)row * K + (kc << 3), vh, vl);
    size_t o = ((size_t)kc * R + row) * 8;
    *(us8*)(hi + o) = vh;
    *(us8*)(lo + o) = vl;
}

// ---------------------------------------------------------------------------
// FLAT split-bf16 MFMA NT GEMM (AITER-flatmm style): NO LDS, no barriers.
// Fragments loaded global->VGPR directly (K8-blocked layout makes each frag a
// coalesced b128: 32 consecutive rows x 16 B). Compiler pipelines loads
// across K-iters with per-use waitcnts. 32x32x16 bf16 MFMA, 3-product split.
// Wave tile: M=64 (2 m-frags) x N=NF*32. Block = 4 waves side by side in n.
// MODE 3: raw fp32 C store.  MODE 2: fused bias + argmax -> packed u64 max.
// ---------------------------------------------------------------------------
template<int MODE, int NF, int K>
__device__ __forceinline__ void flat_body(
    const unsigned short* __restrict__ Ahi, const unsigned short* __restrict__ Alo, int aRows,
    const unsigned short* __restrict__ Bhi, const unsigned short* __restrict__ Blo, int bRows,
    const float* __restrict__ bias, float* __restrict__ C, int ldc,
    unsigned long long* __restrict__ packed,
    int bm, int bn_blk)
{
    const int tid = threadIdx.x;
    const int lane = tid & 63, wave = tid >> 6;
    const int col = lane & 31, kh = lane >> 5;
    const int bn = bn_blk + wave * (NF * 32);

    const size_t aoff = ((size_t)kh * aRows + bm + col) * 8;
    const unsigned short* pah = Ahi + aoff;
    const unsigned short* pal = Alo + aoff;
    const unsigned short* pbh[NF];
    const unsigned short* pbl[NF];
    #pragma unroll
    for (int j = 0; j < NF; ++j) {
        int br = bn + j * 32 + col;
        if (br >= bRows) br = bRows - 1;     // clamp; epilogue masks n >= N
        size_t bo = ((size_t)kh * bRows + br) * 8;
        pbh[j] = Bhi + bo;
        pbl[j] = Blo + bo;
    }
    const size_t astep = (size_t)2 * aRows * 8;   // advance 2 kc per iter
    const size_t bstep = (size_t)2 * bRows * 8;
    const int    a32   = 32 * 8;

    f32x16 acc[2][NF] = {};
    for (int it = 0; it < (K >> 4); ++it) {
        s8v ah0 = *(const s8v*)(pah);
        s8v ah1 = *(const s8v*)(pah + a32);
        s8v al0 = *(const s8v*)(pal);
        s8v al1 = *(const s8v*)(pal + a32);
        s8v bh[NF], bl[NF];
        #pragma unroll
        for (int j = 0; j < NF; ++j) {
            bh[j] = *(const s8v*)(pbh[j]);
            bl[j] = *(const s8v*)(pbl[j]);
        }
        pah += astep; pal += astep;
        #pragma unroll
        for (int j = 0; j < NF; ++j) { pbh[j] += bstep; pbl[j] += bstep; }
        #pragma unroll
        for (int j = 0; j < NF; ++j) {
            acc[0][j] = __builtin_amdgcn_mfma_f32_32x32x16_bf16(ah0, bh[j], acc[0][j], 0, 0, 0);
            acc[1][j] = __builtin_amdgcn_mfma_f32_32x32x16_bf16(ah1, bh[j], acc[1][j], 0, 0, 0);
            acc[0][j] = __builtin_amdgcn_mfma_f32_32x32x16_bf16(ah0, bl[j], acc[0][j], 0, 0, 0);
            acc[1][j] = __builtin_amdgcn_mfma_f32_32x32x16_bf16(ah1, bl[j], acc[1][j], 0, 0, 0);
            acc[0][j] = __builtin_amdgcn_mfma_f32_32x32x16_bf16(al0, bh[j], acc[0][j], 0, 0, 0);
            acc[1][j] = __builtin_amdgcn_mfma_f32_32x32x16_bf16(al1, bh[j], acc[1][j], 0, 0, 0);
        }
    }

    // C/D layout (32x32, m74/m101): col = lane&31, row = (reg&3)+8*(reg>>2)+4*kh
    if (MODE == 3) {
        #pragma unroll
        for (int i = 0; i < 2; ++i)
            #pragma unroll
            for (int rg = 0; rg < 4; ++rg)
                #pragma unroll
                for (int rr = 0; rr < 4; ++rr) {
                    int reg = rg * 4 + rr;
                    int m = bm + i * 32 + rr + rg * 8 + kh * 4;
                    #pragma unroll
                    for (int j = 0; j < NF; ++j) {
                        int n = bn + j * 32 + col;
                        if (n < bRows) C[(size_t)m * ldc + n] = acc[i][j][reg];
                    }
                }
    } else {
        #pragma unroll
        for (int i = 0; i < 2; ++i)
            #pragma unroll
            for (int rg = 0; rg < 4; ++rg)
                #pragma unroll
                for (int rr = 0; rr < 4; ++rr) {
                    int reg = rg * 4 + rr;
                    int m = bm + i * 32 + rr + rg * 8 + kh * 4;
                    unsigned long long best = 0ull;
                    #pragma unroll
                    for (int j = 0; j < NF; ++j) {
                        int n = bn + j * 32 + col;
                        if (n < bRows) {
                            float v = acc[i][j][reg] + bias[n];
                            unsigned int u   = __float_as_uint(v);
                            unsigned int key = (u & 0x80000000u) ? ~u : (u | 0x80000000u);
                            unsigned long long pk =
                                ((unsigned long long)key << 32) |
                                (unsigned long long)(0xFFFFFFFFu - (unsigned)n);
                            best = (pk > best) ? pk : best;
                        }
                    }
                    #pragma unroll
                    for (int sdist = 1; sdist < 32; sdist <<= 1) {
                        unsigned long long o = __shfl_xor(best, sdist, 64);
                        best = (o > best) ? o : best;
                    }
                    if (col == 0) atomicMax(&packed[m], best);
                }
    }
}

// feats: split-K x8 (z = K-chunk of 512), block tile 64x256
__global__ __launch_bounds__(256) void k_feats(
    const unsigned short* Ahi, const unsigned short* Alo,
    const unsigned short* Bhi, const unsigned short* Blo,
    float* C) {
    int kz = blockIdx.z;
    flat_body<3, 2, 512>(Ahi + (size_t)kz * 64 * 1024 * 8, Alo + (size_t)kz * 64 * 1024 * 8, 1024,
                         Bhi + (size_t)kz * 64 * 512 * 8,  Blo + (size_t)kz * 64 * 512 * 8,  512,
                         nullptr, C + (size_t)kz * 1024 * 512, 512, nullptr,
                         blockIdx.y * 64, blockIdx.x * 256);
}
// gates: one-shot, block tile 64x128 (NF=1), templated K (512 prime / 1024 loop)
template<int K>
__global__ __launch_bounds__(256) void k_gates(
    const unsigned short* Ahi, const unsigned short* Alo,
    const unsigned short* Bhi, const unsigned short* Blo,
    float* C) {
    flat_body<3, 1, K>(Ahi, Alo, 1024, Bhi, Blo, NGATE,
                       nullptr, C, NGATE, nullptr,
                       blockIdx.y * 64, blockIdx.x * 128);
}
// logits + argmax: 1D grid 768, XCD-swizzled (6 n-groups of 256 per XCD -> 3 MB B in L2)
__global__ __launch_bounds__(256) void k_logits_argmax(
    const unsigned short* h_hi, const unsigned short* h_lo,
    const unsigned short* wout_hi, const unsigned short* wout_lo,
    const float* bias, unsigned long long* packed) {
    int id = blockIdx.x;
    int xcd = id & 7, slot = id >> 3;
    int bn_grp = xcd * 6 + (slot % 6);   // 0..47 (47 = padding group, fully masked)
    int bm_t = slot / 6;                 // 0..15
    flat_body<2, 2, 512>(h_hi, h_lo, 1024, wout_hi, wout_lo, NVOCAB,
                         bias, nullptr, 0, packed, bm_t * 64, bn_grp * 256);
}

// ---------------------------------------------------------------------------
// feats reduce: sum 8 split-K partials + bias, relu, split -> imgv blocked
// ---------------------------------------------------------------------------
__global__ void feats_reduce8(const float* __restrict__ part, const float* __restrict__ bias,
                              unsigned short* __restrict__ hi, unsigned short* __restrict__ lo) {
    int idx = blockIdx.x * 256 + threadIdx.x;   // 1024*64
    int b = idx >> 6, kc = idx & 63;
    int n = kc << 3;
    float v[8];
    #pragma unroll
    for (int e = 0; e < 8; ++e) v[e] = bias[n + e];
    #pragma unroll
    for (int z = 0; z < 8; ++z) {
        const float* s = part + (size_t)z * 1024 * 512 + (size_t)b * 512 + n;
        #pragma unroll
        for (int e = 0; e < 8; ++e) v[e] += s[e];
    }
    us8 vh, vl;
    #pragma unroll
    for (int e = 0; e < 8; ++e) {
        bfpair q = split2v(fmaxf(v[e], 0.f));
        vh[e] = q.hi; vl[e] = q.lo;
    }
    size_t o = ((size_t)kc * 1024 + b) * 8;
    *(us8*)(hi + o) = vh;
    *(us8*)(lo + o) = vl;
}

// ---------------------------------------------------------------------------
// LSTM pointwise; h -> xh slabs kc=64+j8; emits out[b][t-1] then zeroes packed
// ---------------------------------------------------------------------------
template<bool PRIME>
__global__ void lstm_pw_blk(const float* __restrict__ g0,
                            const float* __restrict__ bsum, float* __restrict__ cbuf,
                            unsigned short* __restrict__ xh_hi, unsigned short* __restrict__ xh_lo,
                            unsigned long long* __restrict__ packed,
                            int* __restrict__ out, int t) {
    int idx = blockIdx.x * 256 + threadIdx.x;   // 1024*64
    int b = idx >> 6, j8 = idx & 63;
    int j = j8 << 3;
    const float* g = g0 + (size_t)b * NGATE;
    float v[4][8];
    #pragma unroll
    for (int gt = 0; gt < 4; ++gt) {
        const float* s = g + gt * 512 + j;
        const float* bs = bsum + gt * 512 + j;
        #pragma unroll
        for (int e = 0; e < 8; ++e) v[gt][e] = s[e] + bs[e];
    }
    float* cb = cbuf + (size_t)b * 512 + j;
    us8 vh, vl;
    #pragma unroll
    for (int e = 0; e < 8; ++e) {
        float si = 1.f / (1.f + expf(-v[0][e]));
        float sf = 1.f / (1.f + expf(-v[1][e]));
        float tg = tanhf(v[2][e]);
        float so = 1.f / (1.f + expf(-v[3][e]));
        float cn = PRIME ? (si * tg) : (sf * cb[e] + si * tg);
        cb[e] = cn;
        bfpair q = split2v(so * tanhf(cn));
        vh[e] = q.hi; vl[e] = q.lo;
    }
    size_t o = ((size_t)(64 + j8) * 1024 + b) * 8;
    *(us8*)(xh_hi + o) = vh;
    *(us8*)(xh_lo + o) = vl;
    if (j8 == 0) {
        if (!PRIME && t > 0) {
            unsigned long long p = packed[b];
            out[b * SEQLEN + (t - 1)] = (int)(0xFFFFFFFFu - (unsigned)(p & 0xFFFFFFFFull));
        }
        packed[b] = 0ull;
    }
}

// ---------------------------------------------------------------------------
// embedding gather + split into xh slabs kc=0..63 (word from packed / START)
// ---------------------------------------------------------------------------
template<int FIRST>
__global__ void gather_blk(const float* __restrict__ emb,
                           const unsigned long long* __restrict__ packed,
                           unsigned short* __restrict__ xh_hi, unsigned short* __restrict__ xh_lo) {
    int idx = blockIdx.x * 256 + threadIdx.x;   // 1024*64
    int b = idx >> 6, kc = idx & 63;
    int word = 1;
    if (!FIRST) {
        unsigned long long p = packed[b];
        word = (int)(0xFFFFFFFFu - (unsigned)(p & 0xFFFFFFFFull)) + 2;
    }
    us8 vh, vl; split8(emb + (size_t)word * 512 + (kc << 3), vh, vl);
    size_t o = ((size_t)kc * 1024 + b) * 8;
    *(us8*)(xh_hi + o) = vh;
    *(us8*)(xh_lo + o) = vl;
}

__global__ void final_out(const unsigned long long* __restrict__ packed, int* __restrict__ out) {
    int b = blockIdx.x * 256 + threadIdx.x;
    if (b < BATCH) {
        unsigned long long p = packed[b];
        out[b * SEQLEN + (SEQLEN - 1)] = (int)(0xFFFFFFFFu - (unsigned)(p & 0xFFFFFFFFull));
    }
}

extern "C" void kernel_launch(void* const* d_in, const int* in_sizes, int n_in,
                              void* d_out, int out_size, void* d_ws, size_t ws_size,
                              hipStream_t stream) {
    const float* img     = (const float*)d_in[0];
    const float* W_feats = (const float*)d_in[1];
    const float* b_feats = (const float*)d_in[2];
    const float* W_ih    = (const float*)d_in[3];
    const float* W_hh    = (const float*)d_in[4];
    const float* b_ih    = (const float*)d_in[5];
    const float* b_hh    = (const float*)d_in[6];
    const float* emb     = (const float*)d_in[7];
    const float* W_out   = (const float*)d_in[8];
    const float* b_out   = (const float*)d_in[9];
    int* out = (int*)d_out;

    const size_t WCAT_H = (size_t)128 * 2048 * 8;
    const size_t WOUT_H = (size_t)64 * NVOCAB * 8;
    const size_t XH_H   = (size_t)128 * 1024 * 8;
    const size_t IMGV_H = (size_t)64 * 1024 * 8;

    char* p = (char*)d_ws;
    unsigned short* wcat_hi = (unsigned short*)p;  p += WCAT_H * 2;
    unsigned short* wcat_lo = (unsigned short*)p;  p += WCAT_H * 2;
    unsigned short* wout_hi = (unsigned short*)p;  p += WOUT_H * 2;
    unsigned short* wout_lo = (unsigned short*)p;  p += WOUT_H * 2;
    unsigned short* xh_hi   = (unsigned short*)p;  p += XH_H * 2;
    unsigned short* xh_lo   = (unsigned short*)p;  p += XH_H * 2;
    unsigned short* imgv_hi = (unsigned short*)p;  p += IMGV_H * 2;
    unsigned short* imgv_lo = (unsigned short*)p;  p += IMGV_H * 2;
    float* cbuf             = (float*)p;           p += (size_t)1024 * 512 * 4;
    float* bsum             = (float*)p;           p += (size_t)NGATE * 4;
    unsigned long long* packed = (unsigned long long*)p;  p += (size_t)1024 * 8;
    float* gates0           = (float*)p;           p += (size_t)1024 * NGATE * 4;
    float* gates1           = (float*)p;           p += (size_t)1024 * NGATE * 4;
    // transient blocked feats inputs alias the not-yet-written wout region
    // (imgb 16 MB + wfb 8 MB = 24 MB <= 24.57 MB):
    unsigned short* imgb_hi = wout_hi;
    unsigned short* imgb_lo = imgb_hi + (size_t)512 * 1024 * 8;
    unsigned short* wfb_hi  = imgb_lo + (size_t)512 * 1024 * 8;
    unsigned short* wfb_lo  = wfb_hi  + (size_t)512 * 512 * 8;
    float* partials = gates0;   // 8 x (1024x512) fp32 = gates0+gates1 region

    // ---- one-time prep
    prep_wcat_blk<<<1024, 256, 0, stream>>>(W_ih, W_hh, b_ih, b_hh, wcat_hi, wcat_lo, bsum);
    prep_blk<<<dim3(4, 512), 256, 0, stream>>>(img,     imgb_hi, imgb_lo, 1024, FEATS);
    prep_blk<<<dim3(2, 512), 256, 0, stream>>>(W_feats, wfb_hi,  wfb_lo,  512,  FEATS);

    // feats: partials[z] = img(chunk z) @ W_feats(chunk z)^T, split-K x8
    k_feats<<<dim3(2, 16, 8), 256, 0, stream>>>(imgb_hi, imgb_lo, wfb_hi, wfb_lo, partials);
    feats_reduce8<<<256, 256, 0, stream>>>(partials, b_feats, imgv_hi, imgv_lo);

    // feats transients dead -> build blocked W_out in place
    prep_blk<<<dim3(47, 64), 256, 0, stream>>>(W_out, wout_hi, wout_lo, NVOCAB, 512);

    // prime LSTM: gates0 = imgv @ W_ih^T (Wcat kc 0..63)
    k_gates<512><<<dim3(16, 16), 256, 0, stream>>>(imgv_hi, imgv_lo, wcat_hi, wcat_lo, gates0);
    lstm_pw_blk<true><<<256, 256, 0, stream>>>(gates0, bsum, cbuf, xh_hi, xh_lo, packed, out, 0);

    for (int t = 0; t < SEQLEN; ++t) {
        if (t == 0) gather_blk<1><<<256, 256, 0, stream>>>(emb, packed, xh_hi, xh_lo);
        else        gather_blk<0><<<256, 256, 0, stream>>>(emb, packed, xh_hi, xh_lo);
        // gates0 = [x|h] @ Wcat^T, one-shot K=1024
        k_gates<1024><<<dim3(16, 16), 256, 0, stream>>>(xh_hi, xh_lo, wcat_hi, wcat_lo, gates0);
        lstm_pw_blk<false><<<256, 256, 0, stream>>>(gates0, bsum, cbuf, xh_hi, xh_lo, packed, out, t);
        k_logits_argmax<<<768, 256, 0, stream>>>(xh_hi + (size_t)64 * 1024 * 8,
                                                 xh_lo + (size_t)64 * 1024 * 8,
                                                 wout_hi, wout_lo, b_out, packed);
    }
    final_out<<<4, 256, 0, stream>>>(packed, out);
}

// Round 8
// 2168.534 us; speedup vs baseline: 1.0934x; 1.0934x over previous
//
#include <hip/hip_runtime.h>
#include <stdint.h>

#define BATCH  1024
#define SEQLEN 15
#define NGATE  2048
#define NVOCAB 11998
#define FEATS  4096

typedef __attribute__((ext_vector_type(8)))  short  s8v;     // 8 bf16 bit patterns
typedef __attribute__((ext_vector_type(16))) float  f32x16;  // 32x32 MFMA acc
typedef __attribute__((ext_vector_type(8)))  unsigned short us8;

__device__ __forceinline__ unsigned short f2bf(float f) {
    unsigned u = __float_as_uint(f);
    u += 0x7FFFu + ((u >> 16) & 1u);
    return (unsigned short)(u >> 16);
}
__device__ __forceinline__ float bf2f(unsigned short h) {
    return __uint_as_float(((unsigned)h) << 16);
}
struct bfpair { unsigned short hi, lo; };
__device__ __forceinline__ bfpair split2v(float v) {
    bfpair r;
    r.hi = f2bf(v);
    r.lo = f2bf(v - bf2f(r.hi));
    return r;
}
__device__ __forceinline__ void split8(const float* __restrict__ s, us8& vh, us8& vl) {
    #pragma unroll
    for (int e = 0; e < 8; ++e) {
        bfpair q = split2v(s[e]);
        vh[e] = q.hi; vl[e] = q.lo;
    }
}

// async 16B-per-lane global->LDS; LDS dest = wave-uniform base, lane i -> base + i*16
__device__ __forceinline__ void async_cp16(const void* g, void* l) {
    __builtin_amdgcn_global_load_lds(
        (const __attribute__((address_space(1))) unsigned int*)g,
        (__attribute__((address_space(3))) unsigned int*)l, 16, 0, 0);
}

// ---------------------------------------------------------------------------
// prep: Wcat blocked [128 kc][2048 row][8] = split([W_ih | W_hh]); bsum
// ---------------------------------------------------------------------------
__global__ void prep_wcat_blk(const float* __restrict__ W_ih, const float* __restrict__ W_hh,
                              const float* __restrict__ b_ih, const float* __restrict__ b_hh,
                              unsigned short* __restrict__ hi, unsigned short* __restrict__ lo,
                              float* __restrict__ bsum) {
    int idx = blockIdx.x * 256 + threadIdx.x;   // 128*2048
    int kc = idx >> 11, row = idx & 2047;
    int k = kc << 3;
    const float* src = (k < 512) ? (W_ih + (size_t)row * 512 + k)
                                 : (W_hh + (size_t)row * 512 + (k - 512));
    us8 vh, vl; split8(src, vh, vl);
    *(us8*)(hi + (size_t)idx * 8) = vh;
    *(us8*)(lo + (size_t)idx * 8) = vl;
    if (idx < NGATE) bsum[idx] = b_ih[idx] + b_hh[idx];
}

// src [R][K] fp32 -> hi/lo [K/8][R][8] bf16. grid: (ceil(R/256), K/8)
__global__ void prep_blk(const float* __restrict__ src,
                         unsigned short* __restrict__ hi, unsigned short* __restrict__ lo,
                         int R, int K) {
    int row = blockIdx.x * 256 + threadIdx.x;
    if (row >= R) return;
    int kc = blockIdx.y;
    us8 vh, vl; split8(src + (size_t)row * K + (kc << 3), vh, vl);
    size_t o = ((size_t)kc * R + row) * 8;
    *(us8*)(hi + o) = vh;
    *(us8*)(lo + o) = vl;
}

// ---------------------------------------------------------------------------
// Split-bf16 MFMA NT GEMM body (round-5 proven structure): single-buffered
// global_load_lds staging, K8-blocked operands [kc][rows][8], 128x128 tile,
// 4 waves (2x2 of 64x64), 32x32x16 bf16 MFMA, 3-product split (hh+hl+lh).
// LDS [4 arr][4 kc][128 row][8] = 32 KB, passed in by the caller.
// MODE 3: raw fp32 C store.  MODE 2: fused bias + argmax -> packed u64 max.
// ---------------------------------------------------------------------------
template<int MODE>
__device__ __forceinline__ void mfma_blk_body(
    short* smem,
    const unsigned short* __restrict__ Ahi, const unsigned short* __restrict__ Alo, int aRows,
    const unsigned short* __restrict__ Bhi, const unsigned short* __restrict__ Blo, int bRows,
    const float* __restrict__ bias,
    float* __restrict__ C, int ldc,
    unsigned long long* __restrict__ packed,
    int K, int bm, int bn)
{
    short* sAhi = smem;
    short* sAlo = smem + 4 * 128 * 8;
    short* sBhi = smem + 2 * 4 * 128 * 8;
    short* sBlo = smem + 3 * 4 * 128 * 8;

    const int tid  = threadIdx.x;
    const int lane = tid & 63, wave = tid >> 6;
    const int wr = (wave & 1) * 64, wc = (wave >> 1) * 64;
    const int col = lane & 31, kh = lane >> 5;

    f32x16 acc[2][2] = {};

    for (int k0 = 0; k0 < K; k0 += 32) {
        const int kc0 = k0 >> 3;
        __syncthreads();
        #pragma unroll
        for (int p = 0; p < 2; ++p) {
            int s    = p * 4 + wave;
            int kc_l = s >> 1, rh = s & 1;
            int rl   = rh * 64 + lane;
            int lo_  = (kc_l * 128 + rh * 64) * 8;   // wave-uniform LDS short offset
            size_t ga = ((size_t)(kc0 + kc_l) * aRows + (bm + rl)) * 8;
            async_cp16(Ahi + ga, sAhi + lo_);
            async_cp16(Alo + ga, sAlo + lo_);
            int brow = bn + rl; if (brow > bRows - 1) brow = bRows - 1;
            size_t gb = ((size_t)(kc0 + kc_l) * bRows + brow) * 8;
            async_cp16(Bhi + gb, sBhi + lo_);
            async_cp16(Blo + gb, sBlo + lo_);
        }
        __syncthreads();

        #pragma unroll
        for (int st = 0; st < 2; ++st) {
            int off = (2 * st + kh) * 128 * 8;
            s8v ah0 = *(const s8v*)(sAhi + off + (wr + col) * 8);
            s8v ah1 = *(const s8v*)(sAhi + off + (wr + 32 + col) * 8);
            s8v al0 = *(const s8v*)(sAlo + off + (wr + col) * 8);
            s8v al1 = *(const s8v*)(sAlo + off + (wr + 32 + col) * 8);
            s8v bh0 = *(const s8v*)(sBhi + off + (wc + col) * 8);
            s8v bh1 = *(const s8v*)(sBhi + off + (wc + 32 + col) * 8);
            s8v bl0 = *(const s8v*)(sBlo + off + (wc + col) * 8);
            s8v bl1 = *(const s8v*)(sBlo + off + (wc + 32 + col) * 8);
            acc[0][0] = __builtin_amdgcn_mfma_f32_32x32x16_bf16(ah0, bh0, acc[0][0], 0, 0, 0);
            acc[0][1] = __builtin_amdgcn_mfma_f32_32x32x16_bf16(ah0, bh1, acc[0][1], 0, 0, 0);
            acc[1][0] = __builtin_amdgcn_mfma_f32_32x32x16_bf16(ah1, bh0, acc[1][0], 0, 0, 0);
            acc[1][1] = __builtin_amdgcn_mfma_f32_32x32x16_bf16(ah1, bh1, acc[1][1], 0, 0, 0);
            acc[0][0] = __builtin_amdgcn_mfma_f32_32x32x16_bf16(ah0, bl0, acc[0][0], 0, 0, 0);
            acc[0][1] = __builtin_amdgcn_mfma_f32_32x32x16_bf16(ah0, bl1, acc[0][1], 0, 0, 0);
            acc[1][0] = __builtin_amdgcn_mfma_f32_32x32x16_bf16(ah1, bl0, acc[1][0], 0, 0, 0);
            acc[1][1] = __builtin_amdgcn_mfma_f32_32x32x16_bf16(ah1, bl1, acc[1][1], 0, 0, 0);
            acc[0][0] = __builtin_amdgcn_mfma_f32_32x32x16_bf16(al0, bh0, acc[0][0], 0, 0, 0);
            acc[0][1] = __builtin_amdgcn_mfma_f32_32x32x16_bf16(al0, bh1, acc[0][1], 0, 0, 0);
            acc[1][0] = __builtin_amdgcn_mfma_f32_32x32x16_bf16(al1, bh0, acc[1][0], 0, 0, 0);
            acc[1][1] = __builtin_amdgcn_mfma_f32_32x32x16_bf16(al1, bh1, acc[1][1], 0, 0, 0);
        }
    }

    // C/D layout (32x32, m74/m101): col = lane&31, row = (reg&3)+8*(reg>>2)+4*kh
    if (MODE == 3) {
        #pragma unroll
        for (int i = 0; i < 2; ++i)
            #pragma unroll
            for (int rg = 0; rg < 4; ++rg)
                #pragma unroll
                for (int rr = 0; rr < 4; ++rr) {
                    int reg = rg * 4 + rr;
                    int m = bm + wr + i * 32 + rr + rg * 8 + kh * 4;
                    #pragma unroll
                    for (int j = 0; j < 2; ++j) {
                        int n = bn + wc + j * 32 + col;
                        if (n < bRows) C[(size_t)m * ldc + n] = acc[i][j][reg];
                    }
                }
    } else {
        #pragma unroll
        for (int i = 0; i < 2; ++i)
            #pragma unroll
            for (int rg = 0; rg < 4; ++rg)
                #pragma unroll
                for (int rr = 0; rr < 4; ++rr) {
                    int reg = rg * 4 + rr;
                    int m = bm + wr + i * 32 + rr + rg * 8 + kh * 4;
                    unsigned long long best = 0ull;
                    #pragma unroll
                    for (int j = 0; j < 2; ++j) {
                        int n = bn + wc + j * 32 + col;
                        if (n < bRows) {
                            float v = acc[i][j][reg] + bias[n];
                            unsigned int u   = __float_as_uint(v);
                            unsigned int key = (u & 0x80000000u) ? ~u : (u | 0x80000000u);
                            unsigned long long pk =
                                ((unsigned long long)key << 32) |
                                (unsigned long long)(0xFFFFFFFFu - (unsigned)n);
                            best = (pk > best) ? pk : best;
                        }
                    }
                    #pragma unroll
                    for (int sdist = 1; sdist < 32; sdist <<= 1) {
                        unsigned long long o = __shfl_xor(best, sdist, 64);
                        best = (o > best) ? o : best;
                    }
                    if (col == 0) atomicMax(&packed[m], best);
                }
    }
}

// ---------------------------------------------------------------------------
// combined per-step kernel: blocks 0..767 = logits(h)+argmax (XCD-swizzled);
// blocks 768..895 = gates_h = h @ W_hh^T (independent of argmax -> rides in
// the logits kernel's idle issue slots, m114 co-schedule).
// ---------------------------------------------------------------------------
__global__ __launch_bounds__(256) void k_combined(
    const unsigned short* __restrict__ h_hi, const unsigned short* __restrict__ h_lo,
    const unsigned short* __restrict__ wout_hi, const unsigned short* __restrict__ wout_lo,
    const unsigned short* __restrict__ whh_hi, const unsigned short* __restrict__ whh_lo,
    const float* __restrict__ b_out, float* __restrict__ gates0,
    unsigned long long* __restrict__ packed) {
    __shared__ short smem[16384];
    int id = blockIdx.x;
    if (id < 768) {
        int xcd = id & 7, slot = id >> 3;
        int bn_t = xcd * 12 + (slot % 12);   // 12 n-tiles (3 MB of W_out) per XCD L2
        int bm_t = slot / 12;
        mfma_blk_body<2>(smem, h_hi, h_lo, 1024, wout_hi, wout_lo, NVOCAB,
                         b_out, nullptr, 0, packed, 512, bm_t * 128, bn_t * 128);
    } else {
        int g = id - 768;                    // 0..127: N=2048 -> 16 n-tiles, M -> 8
        mfma_blk_body<3>(smem, h_hi, h_lo, 1024, whh_hi, whh_lo, NGATE,
                         nullptr, gates0, NGATE, nullptr, 512,
                         (g >> 4) * 128, (g & 15) * 128);
    }
}

// generic 1024xNGATE K=512 gates GEMM (prime, gates_h0, gates_x). grid (16,8)
__global__ __launch_bounds__(256) void k_gates(
    const unsigned short* __restrict__ Ahi, const unsigned short* __restrict__ Alo,
    const unsigned short* __restrict__ Bhi, const unsigned short* __restrict__ Blo,
    float* __restrict__ C) {
    __shared__ short smem[16384];
    mfma_blk_body<3>(smem, Ahi, Alo, 1024, Bhi, Blo, NGATE, nullptr, C, NGATE,
                     nullptr, 512, blockIdx.y * 128, blockIdx.x * 128);
}

// feats: split-K x8 (z = chunk of 512). grid (4,8,8)
__global__ __launch_bounds__(256) void k_feats(
    const unsigned short* __restrict__ Ahi, const unsigned short* __restrict__ Alo,
    const unsigned short* __restrict__ Bhi, const unsigned short* __restrict__ Blo,
    float* __restrict__ C) {
    __shared__ short smem[16384];
    int kz = blockIdx.z;
    mfma_blk_body<3>(smem,
                     Ahi + (size_t)kz * 64 * 1024 * 8, Alo + (size_t)kz * 64 * 1024 * 8, 1024,
                     Bhi + (size_t)kz * 64 * 512 * 8,  Blo + (size_t)kz * 64 * 512 * 8,  512,
                     nullptr, C + (size_t)kz * 1024 * 512, 512, nullptr, 512,
                     blockIdx.y * 128, blockIdx.x * 128);
}

// ---------------------------------------------------------------------------
// feats reduce: sum 8 split-K partials + bias, relu, split -> imgv blocked
// ---------------------------------------------------------------------------
__global__ void feats_reduce8(const float* __restrict__ part, const float* __restrict__ bias,
                              unsigned short* __restrict__ hi, unsigned short* __restrict__ lo) {
    int idx = blockIdx.x * 256 + threadIdx.x;   // 1024*64
    int b = idx >> 6, kc = idx & 63;
    int n = kc << 3;
    float v[8];
    #pragma unroll
    for (int e = 0; e < 8; ++e) v[e] = bias[n + e];
    #pragma unroll
    for (int z = 0; z < 8; ++z) {
        const float* s = part + (size_t)z * 1024 * 512 + (size_t)b * 512 + n;
        #pragma unroll
        for (int e = 0; e < 8; ++e) v[e] += s[e];
    }
    us8 vh, vl;
    #pragma unroll
    for (int e = 0; e < 8; ++e) {
        bfpair q = split2v(fmaxf(v[e], 0.f));
        vh[e] = q.hi; vl[e] = q.lo;
    }
    size_t o = ((size_t)kc * 1024 + b) * 8;
    *(us8*)(hi + o) = vh;
    *(us8*)(lo + o) = vl;
}

// ---------------------------------------------------------------------------
// LSTM pointwise: g0 (+g1) + bsum -> c, h; h -> xh slabs kc=64+j8;
// emits out[b][t-1] from packed (word id) then zeroes packed.
// ---------------------------------------------------------------------------
template<bool PRIME>
__global__ void lstm_pw_blk(const float* __restrict__ g0, const float* __restrict__ g1,
                            const float* __restrict__ bsum, float* __restrict__ cbuf,
                            unsigned short* __restrict__ xh_hi, unsigned short* __restrict__ xh_lo,
                            unsigned long long* __restrict__ packed,
                            int* __restrict__ out, int t) {
    int idx = blockIdx.x * 256 + threadIdx.x;   // 1024*64
    int b = idx >> 6, j8 = idx & 63;
    int j = j8 << 3;
    const float* g = g0 + (size_t)b * NGATE;
    float v[4][8];
    #pragma unroll
    for (int gt = 0; gt < 4; ++gt) {
        const float* s = g + gt * 512 + j;
        const float* bs = bsum + gt * 512 + j;
        #pragma unroll
        for (int e = 0; e < 8; ++e) v[gt][e] = s[e] + bs[e];
    }
    if (!PRIME) {
        const float* h2 = g1 + (size_t)b * NGATE;
        #pragma unroll
        for (int gt = 0; gt < 4; ++gt) {
            const float* s = h2 + gt * 512 + j;
            #pragma unroll
            for (int e = 0; e < 8; ++e) v[gt][e] += s[e];
        }
    }
    float* cb = cbuf + (size_t)b * 512 + j;
    us8 vh, vl;
    #pragma unroll
    for (int e = 0; e < 8; ++e) {
        float si = 1.f / (1.f + expf(-v[0][e]));
        float sf = 1.f / (1.f + expf(-v[1][e]));
        float tg = tanhf(v[2][e]);
        float so = 1.f / (1.f + expf(-v[3][e]));
        float cn = PRIME ? (si * tg) : (sf * cb[e] + si * tg);
        cb[e] = cn;
        bfpair q = split2v(so * tanhf(cn));
        vh[e] = q.hi; vl[e] = q.lo;
    }
    size_t o = ((size_t)(64 + j8) * 1024 + b) * 8;
    *(us8*)(xh_hi + o) = vh;
    *(us8*)(xh_lo + o) = vl;
    if (j8 == 0) {
        if (!PRIME && t > 0) {
            unsigned long long p = packed[b];
            out[b * SEQLEN + (t - 1)] = (int)(0xFFFFFFFFu - (unsigned)(p & 0xFFFFFFFFull));
        }
        packed[b] = 0ull;
    }
}

// ---------------------------------------------------------------------------
// embedding gather + split into xh slabs kc=0..63 (word from packed / START)
// ---------------------------------------------------------------------------
template<int FIRST>
__global__ void gather_blk(const float* __restrict__ emb,
                           const unsigned long long* __restrict__ packed,
                           unsigned short* __restrict__ xh_hi, unsigned short* __restrict__ xh_lo) {
    int idx = blockIdx.x * 256 + threadIdx.x;   // 1024*64
    int b = idx >> 6, kc = idx & 63;
    int word = 1;
    if (!FIRST) {
        unsigned long long p = packed[b];
        word = (int)(0xFFFFFFFFu - (unsigned)(p & 0xFFFFFFFFull)) + 2;
    }
    us8 vh, vl; split8(emb + (size_t)word * 512 + (kc << 3), vh, vl);
    size_t o = ((size_t)kc * 1024 + b) * 8;
    *(us8*)(xh_hi + o) = vh;
    *(us8*)(xh_lo + o) = vl;
}

__global__ void final_out(const unsigned long long* __restrict__ packed, int* __restrict__ out) {
    int b = blockIdx.x * 256 + threadIdx.x;
    if (b < BATCH) {
        unsigned long long p = packed[b];
        out[b * SEQLEN + (SEQLEN - 1)] = (int)(0xFFFFFFFFu - (unsigned)(p & 0xFFFFFFFFull));
    }
}

extern "C" void kernel_launch(void* const* d_in, const int* in_sizes, int n_in,
                              void* d_out, int out_size, void* d_ws, size_t ws_size,
                              hipStream_t stream) {
    const float* img     = (const float*)d_in[0];
    const float* W_feats = (const float*)d_in[1];
    const float* b_feats = (const float*)d_in[2];
    const float* W_ih    = (const float*)d_in[3];
    const float* W_hh    = (const float*)d_in[4];
    const float* b_ih    = (const float*)d_in[5];
    const float* b_hh    = (const float*)d_in[6];
    const float* emb     = (const float*)d_in[7];
    const float* W_out   = (const float*)d_in[8];
    const float* b_out   = (const float*)d_in[9];
    int* out = (int*)d_out;

    const size_t WCAT_H = (size_t)128 * 2048 * 8;
    const size_t WOUT_H = (size_t)64 * NVOCAB * 8;
    const size_t XH_H   = (size_t)128 * 1024 * 8;
    const size_t IMGV_H = (size_t)64 * 1024 * 8;

    char* p = (char*)d_ws;
    unsigned short* wcat_hi = (unsigned short*)p;  p += WCAT_H * 2;
    unsigned short* wcat_lo = (unsigned short*)p;  p += WCAT_H * 2;
    unsigned short* wout_hi = (unsigned short*)p;  p += WOUT_H * 2;
    unsigned short* wout_lo = (unsigned short*)p;  p += WOUT_H * 2;
    unsigned short* xh_hi   = (unsigned short*)p;  p += XH_H * 2;
    unsigned short* xh_lo   = (unsigned short*)p;  p += XH_H * 2;
    unsigned short* imgv_hi = (unsigned short*)p;  p += IMGV_H * 2;
    unsigned short* imgv_lo = (unsigned short*)p;  p += IMGV_H * 2;
    float* cbuf             = (float*)p;           p += (size_t)1024 * 512 * 4;
    float* bsum             = (float*)p;           p += (size_t)NGATE * 4;
    unsigned long long* packed = (unsigned long long*)p;  p += (size_t)1024 * 8;
    float* gates0           = (float*)p;           p += (size_t)1024 * NGATE * 4;
    float* gates1           = (float*)p;           p += (size_t)1024 * NGATE * 4;
    // transient blocked feats inputs alias the not-yet-written wout region
    unsigned short* imgb_hi = wout_hi;
    unsigned short* imgb_lo = imgb_hi + (size_t)512 * 1024 * 8;
    unsigned short* wfb_hi  = imgb_lo + (size_t)512 * 1024 * 8;
    unsigned short* wfb_lo  = wfb_hi  + (size_t)512 * 512 * 8;
    float* partials = gates0;   // 8 x (1024x512) fp32 = gates0+gates1 region

    const unsigned short* whh_hi = wcat_hi + (size_t)64 * 2048 * 8;  // Wcat kc 64..127
    const unsigned short* whh_lo = wcat_lo + (size_t)64 * 2048 * 8;
    const unsigned short* h_hi   = xh_hi + (size_t)64 * 1024 * 8;    // h slabs
    const unsigned short* h_lo   = xh_lo + (size_t)64 * 1024 * 8;

    // ---- one-time prep
    prep_wcat_blk<<<1024, 256, 0, stream>>>(W_ih, W_hh, b_ih, b_hh, wcat_hi, wcat_lo, bsum);
    prep_blk<<<dim3(4, 512), 256, 0, stream>>>(img,     imgb_hi, imgb_lo, 1024, FEATS);
    prep_blk<<<dim3(2, 512), 256, 0, stream>>>(W_feats, wfb_hi,  wfb_lo,  512,  FEATS);

    // feats: partials[z] = img(chunk z) @ W_feats(chunk z)^T, split-K x8
    k_feats<<<dim3(4, 8, 8), 256, 0, stream>>>(imgb_hi, imgb_lo, wfb_hi, wfb_lo, partials);
    feats_reduce8<<<256, 256, 0, stream>>>(partials, b_feats, imgv_hi, imgv_lo);

    // feats transients dead -> build blocked W_out in place
    prep_blk<<<dim3(47, 64), 256, 0, stream>>>(W_out, wout_hi, wout_lo, NVOCAB, 512);

    // prime LSTM: gates0 = imgv @ W_ih^T ; h_P (also zeroes packed)
    k_gates<<<dim3(16, 8), 256, 0, stream>>>(imgv_hi, imgv_lo, wcat_hi, wcat_lo, gates0);
    lstm_pw_blk<true><<<256, 256, 0, stream>>>(gates0, nullptr, bsum, cbuf,
                                               xh_hi, xh_lo, packed, out, 0);
    // gates_h for t=0: gates0 = h_P @ W_hh^T
    k_gates<<<dim3(16, 8), 256, 0, stream>>>(h_hi, h_lo, whh_hi, whh_lo, gates0);

    for (int t = 0; t < SEQLEN; ++t) {
        // x(t) = emb[word(t-1)] (START at t=0; word from packed(t-1))
        if (t == 0) gather_blk<1><<<256, 256, 0, stream>>>(emb, packed, xh_hi, xh_lo);
        else        gather_blk<0><<<256, 256, 0, stream>>>(emb, packed, xh_hi, xh_lo);
        // gates1 = x(t) @ W_ih^T
        k_gates<<<dim3(16, 8), 256, 0, stream>>>(xh_hi, xh_lo, wcat_hi, wcat_lo, gates1);
        // h(t) = lstm(gates0 + gates1); emits out[t-1]; zeroes packed
        lstm_pw_blk<false><<<256, 256, 0, stream>>>(gates0, gates1, bsum, cbuf,
                                                    xh_hi, xh_lo, packed, out, t);
        // logits(h(t)) + argmax -> packed(t); concurrently gates0 = h(t) @ W_hh^T
        k_combined<<<896, 256, 0, stream>>>(h_hi, h_lo, wout_hi, wout_lo,
                                            whh_hi, whh_lo, b_out, gates0, packed);
    }
    final_out<<<4, 256, 0, stream>>>(packed, out);
}

// Round 9
// 1763.575 us; speedup vs baseline: 1.3444x; 1.2296x over previous
//
#include <hip/hip_runtime.h>
#include <stdint.h>

#define BATCH  1024
#define SEQLEN 15
#define NGATE  2048
#define NVOCAB 11998
#define FEATS  4096

typedef __attribute__((ext_vector_type(8)))  short  s8v;     // 8 bf16 bit patterns
typedef __attribute__((ext_vector_type(16))) float  f32x16;  // 32x32 MFMA acc
typedef __attribute__((ext_vector_type(8)))  unsigned short us8;

__device__ __forceinline__ unsigned short f2bf(float f) {
    unsigned u = __float_as_uint(f);
    u += 0x7FFFu + ((u >> 16) & 1u);
    return (unsigned short)(u >> 16);
}
__device__ __forceinline__ float bf2f(unsigned short h) {
    return __uint_as_float(((unsigned)h) << 16);
}
struct bfpair { unsigned short hi, lo; };
__device__ __forceinline__ bfpair split2v(float v) {
    bfpair r;
    r.hi = f2bf(v);
    r.lo = f2bf(v - bf2f(r.hi));
    return r;
}
__device__ __forceinline__ void split8(const float* __restrict__ s, us8& vh, us8& vl) {
    #pragma unroll
    for (int e = 0; e < 8; ++e) {
        bfpair q = split2v(s[e]);
        vh[e] = q.hi; vl[e] = q.lo;
    }
}

// async 16B-per-lane global->LDS; LDS dest = wave-uniform base + lane*16
__device__ __forceinline__ void async_cp16(const void* g, void* l) {
    __builtin_amdgcn_global_load_lds(
        (const __attribute__((address_space(1))) unsigned int*)g,
        (__attribute__((address_space(3))) unsigned int*)l, 16, 0, 0);
}

// ---------------------------------------------------------------------------
// prep: Wcat blocked [128 kc][2048 row][8] = split([W_ih | W_hh]); bsum
// ---------------------------------------------------------------------------
__global__ void prep_wcat_blk(const float* __restrict__ W_ih, const float* __restrict__ W_hh,
                              const float* __restrict__ b_ih, const float* __restrict__ b_hh,
                              unsigned short* __restrict__ hi, unsigned short* __restrict__ lo,
                              float* __restrict__ bsum) {
    int idx = blockIdx.x * 256 + threadIdx.x;   // 128*2048
    int kc = idx >> 11, row = idx & 2047;
    int k = kc << 3;
    const float* src = (k < 512) ? (W_ih + (size_t)row * 512 + k)
                                 : (W_hh + (size_t)row * 512 + (k - 512));
    us8 vh, vl; split8(src, vh, vl);
    *(us8*)(hi + (size_t)idx * 8) = vh;
    *(us8*)(lo + (size_t)idx * 8) = vl;
    if (idx < NGATE) bsum[idx] = b_ih[idx] + b_hh[idx];
}

// src [R][K] fp32 -> hi/lo [K/8][R][8] bf16. grid: (ceil(R/256), K/8)
__global__ void prep_blk(const float* __restrict__ src,
                         unsigned short* __restrict__ hi, unsigned short* __restrict__ lo,
                         int R, int K) {
    int row = blockIdx.x * 256 + threadIdx.x;
    if (row >= R) return;
    int kc = blockIdx.y;
    us8 vh, vl; split8(src + (size_t)row * K + (kc << 3), vh, vl);
    size_t o = ((size_t)kc * R + row) * 8;
    *(us8*)(hi + o) = vh;
    *(us8*)(lo + o) = vl;
}

// ---------------------------------------------------------------------------
// Round-5 proven GEMM body: single-buffered global_load_lds staging,
// K8-blocked operands [kc][rows][8], 128x128 tile, 4 waves (2x2 of 64x64),
// 32x32x16 bf16 MFMA, 3-product split. MODE 3 store only (gates/feats).
// ---------------------------------------------------------------------------
__device__ __forceinline__ void mfma_blk_store(
    const unsigned short* __restrict__ Ahi, const unsigned short* __restrict__ Alo, int aRows,
    const unsigned short* __restrict__ Bhi, const unsigned short* __restrict__ Blo, int bRows,
    float* __restrict__ C, int ldc,
    int K, size_t akstride, size_t bkstride, size_t czstride)
{
    __shared__ short smem[4 * 4 * 128 * 8];   // 32 KB
    short* sAhi = smem;
    short* sAlo = smem + 4 * 128 * 8;
    short* sBhi = smem + 2 * 4 * 128 * 8;
    short* sBlo = smem + 3 * 4 * 128 * 8;

    const int kz = blockIdx.z;
    Ahi += (size_t)kz * akstride;  Alo += (size_t)kz * akstride;
    Bhi += (size_t)kz * bkstride;  Blo += (size_t)kz * bkstride;
    C   += (size_t)kz * czstride;

    const int tid  = threadIdx.x;
    const int lane = tid & 63, wave = tid >> 6;
    const int wr = (wave & 1) * 64, wc = (wave >> 1) * 64;
    const int col = lane & 31, kh = lane >> 5;
    const int bm = blockIdx.y * 128, bn = blockIdx.x * 128;

    f32x16 acc[2][2] = {};

    for (int k0 = 0; k0 < K; k0 += 32) {
        const int kc0 = k0 >> 3;
        __syncthreads();
        #pragma unroll
        for (int p = 0; p < 2; ++p) {
            int s    = p * 4 + wave;
            int kc_l = s >> 1, rh = s & 1;
            int rl   = rh * 64 + lane;
            int lo_  = (kc_l * 128 + rh * 64) * 8;
            size_t ga = ((size_t)(kc0 + kc_l) * aRows + (bm + rl)) * 8;
            async_cp16(Ahi + ga, sAhi + lo_);
            async_cp16(Alo + ga, sAlo + lo_);
            int brow = bn + rl; if (brow > bRows - 1) brow = bRows - 1;
            size_t gb = ((size_t)(kc0 + kc_l) * bRows + brow) * 8;
            async_cp16(Bhi + gb, sBhi + lo_);
            async_cp16(Blo + gb, sBlo + lo_);
        }
        __syncthreads();

        #pragma unroll
        for (int st = 0; st < 2; ++st) {
            int off = (2 * st + kh) * 128 * 8;
            s8v ah0 = *(const s8v*)(sAhi + off + (wr + col) * 8);
            s8v ah1 = *(const s8v*)(sAhi + off + (wr + 32 + col) * 8);
            s8v al0 = *(const s8v*)(sAlo + off + (wr + col) * 8);
            s8v al1 = *(const s8v*)(sAlo + off + (wr + 32 + col) * 8);
            s8v bh0 = *(const s8v*)(sBhi + off + (wc + col) * 8);
            s8v bh1 = *(const s8v*)(sBhi + off + (wc + 32 + col) * 8);
            s8v bl0 = *(const s8v*)(sBlo + off + (wc + col) * 8);
            s8v bl1 = *(const s8v*)(sBlo + off + (wc + 32 + col) * 8);
            acc[0][0] = __builtin_amdgcn_mfma_f32_32x32x16_bf16(ah0, bh0, acc[0][0], 0, 0, 0);
            acc[0][1] = __builtin_amdgcn_mfma_f32_32x32x16_bf16(ah0, bh1, acc[0][1], 0, 0, 0);
            acc[1][0] = __builtin_amdgcn_mfma_f32_32x32x16_bf16(ah1, bh0, acc[1][0], 0, 0, 0);
            acc[1][1] = __builtin_amdgcn_mfma_f32_32x32x16_bf16(ah1, bh1, acc[1][1], 0, 0, 0);
            acc[0][0] = __builtin_amdgcn_mfma_f32_32x32x16_bf16(ah0, bl0, acc[0][0], 0, 0, 0);
            acc[0][1] = __builtin_amdgcn_mfma_f32_32x32x16_bf16(ah0, bl1, acc[0][1], 0, 0, 0);
            acc[1][0] = __builtin_amdgcn_mfma_f32_32x32x16_bf16(ah1, bl0, acc[1][0], 0, 0, 0);
            acc[1][1] = __builtin_amdgcn_mfma_f32_32x32x16_bf16(ah1, bl1, acc[1][1], 0, 0, 0);
            acc[0][0] = __builtin_amdgcn_mfma_f32_32x32x16_bf16(al0, bh0, acc[0][0], 0, 0, 0);
            acc[0][1] = __builtin_amdgcn_mfma_f32_32x32x16_bf16(al0, bh1, acc[0][1], 0, 0, 0);
            acc[1][0] = __builtin_amdgcn_mfma_f32_32x32x16_bf16(al1, bh0, acc[1][0], 0, 0, 0);
            acc[1][1] = __builtin_amdgcn_mfma_f32_32x32x16_bf16(al1, bh1, acc[1][1], 0, 0, 0);
        }
    }

    // C/D layout (32x32, m74/m101): col = lane&31, row = (reg&3)+8*(reg>>2)+4*kh
    #pragma unroll
    for (int i = 0; i < 2; ++i)
        #pragma unroll
        for (int rg = 0; rg < 4; ++rg)
            #pragma unroll
            for (int rr = 0; rr < 4; ++rr) {
                int reg = rg * 4 + rr;
                int m = bm + wr + i * 32 + rr + rg * 8 + kh * 4;
                #pragma unroll
                for (int j = 0; j < 2; ++j) {
                    int n = bn + wc + j * 32 + col;
                    if (n < bRows) C[(size_t)m * ldc + n] = acc[i][j][reg];
                }
            }
}

__global__ __launch_bounds__(256) void k_gemm_gates(
    const unsigned short* Ahi, const unsigned short* Alo,
    const unsigned short* Bhi, const unsigned short* Blo,
    float* C, size_t aks, size_t bks, size_t czs) {
    mfma_blk_store(Ahi, Alo, 1024, Bhi, Blo, NGATE, C, NGATE, 512, aks, bks, czs);
}
__global__ __launch_bounds__(256) void k_gemm_feats(
    const unsigned short* Ahi, const unsigned short* Alo,
    const unsigned short* Bhi, const unsigned short* Blo,
    float* C) {
    mfma_blk_store(Ahi, Alo, 1024, Bhi, Blo, 512, C, 512, 512,
                   (size_t)64 * 1024 * 8, (size_t)64 * 512 * 8, (size_t)1024 * 512);
}

// ---------------------------------------------------------------------------
// NEW logits kernel (Design B): 128 threads = 2 waves stacked in m, wave tile
// 64x128 (2 m-frags x 4 n-frags, 128 acc VGPRs), same 128x128 block tile,
// same 32 KB staging, same (94,8) grid. 48 MFMA per wave per barrier (2x r5)
// -> halves barrier count per unit work. Fused bias + argmax epilogue.
// ---------------------------------------------------------------------------
__global__ __launch_bounds__(128, 2) void k_logits_argmax(
    const unsigned short* __restrict__ h_hi, const unsigned short* __restrict__ h_lo,
    const unsigned short* __restrict__ wout_hi, const unsigned short* __restrict__ wout_lo,
    const float* __restrict__ bias, unsigned long long* __restrict__ packed) {
    __shared__ short smem[4 * 4 * 128 * 8];   // 32 KB
    short* sAhi = smem;
    short* sAlo = smem + 4096;
    short* sBhi = smem + 8192;
    short* sBlo = smem + 12288;

    const int tid = threadIdx.x;
    const int lane = tid & 63, wave = tid >> 6;   // 2 waves
    const int wr = wave * 64;
    const int col = lane & 31, kh = lane >> 5;
    const int bm = blockIdx.y * 128, bn = blockIdx.x * 128;
    const int aRows = 1024, bRows = NVOCAB;

    f32x16 acc[2][4] = {};

    for (int k0 = 0; k0 < 512; k0 += 32) {
        const int kc0 = k0 >> 3;
        __syncthreads();
        // 32 cp16 slabs, 16 per wave: s -> (arr, kc_l, row-half)
        #pragma unroll
        for (int p = 0; p < 16; ++p) {
            int s = p * 2 + wave;              // 0..31, wave-uniform per p
            int arr = s >> 3, rem = s & 7;
            int kc_l = rem >> 1, rh = rem & 1;
            int rl = rh * 64 + lane;
            int lo_ = (kc_l * 128 + rh * 64) * 8;
            if (arr < 2) {
                size_t ga = ((size_t)(kc0 + kc_l) * aRows + (bm + rl)) * 8;
                async_cp16((arr == 0 ? h_hi : h_lo) + ga, (arr == 0 ? sAhi : sAlo) + lo_);
            } else {
                int brow = bn + rl; if (brow > bRows - 1) brow = bRows - 1;
                size_t gb = ((size_t)(kc0 + kc_l) * bRows + brow) * 8;
                async_cp16((arr == 2 ? wout_hi : wout_lo) + gb, (arr == 2 ? sBhi : sBlo) + lo_);
            }
        }
        __syncthreads();

        #pragma unroll
        for (int st = 0; st < 2; ++st) {
            int off = (2 * st + kh) * 128 * 8;
            s8v ah0 = *(const s8v*)(sAhi + off + (wr + col) * 8);
            s8v ah1 = *(const s8v*)(sAhi + off + (wr + 32 + col) * 8);
            s8v al0 = *(const s8v*)(sAlo + off + (wr + col) * 8);
            s8v al1 = *(const s8v*)(sAlo + off + (wr + 32 + col) * 8);
            #pragma unroll
            for (int j = 0; j < 4; ++j) {
                s8v bh = *(const s8v*)(sBhi + off + (j * 32 + col) * 8);
                s8v bl = *(const s8v*)(sBlo + off + (j * 32 + col) * 8);
                acc[0][j] = __builtin_amdgcn_mfma_f32_32x32x16_bf16(ah0, bh, acc[0][j], 0, 0, 0);
                acc[1][j] = __builtin_amdgcn_mfma_f32_32x32x16_bf16(ah1, bh, acc[1][j], 0, 0, 0);
                acc[0][j] = __builtin_amdgcn_mfma_f32_32x32x16_bf16(ah0, bl, acc[0][j], 0, 0, 0);
                acc[1][j] = __builtin_amdgcn_mfma_f32_32x32x16_bf16(ah1, bl, acc[1][j], 0, 0, 0);
                acc[0][j] = __builtin_amdgcn_mfma_f32_32x32x16_bf16(al0, bh, acc[0][j], 0, 0, 0);
                acc[1][j] = __builtin_amdgcn_mfma_f32_32x32x16_bf16(al1, bh, acc[1][j], 0, 0, 0);
            }
        }
    }

    // argmax epilogue: col = lane&31, row = (reg&3)+8*(reg>>2)+4*kh
    #pragma unroll
    for (int i = 0; i < 2; ++i)
        #pragma unroll
        for (int rg = 0; rg < 4; ++rg)
            #pragma unroll
            for (int rr = 0; rr < 4; ++rr) {
                int reg = rg * 4 + rr;
                int m = bm + wr + i * 32 + rr + rg * 8 + kh * 4;
                unsigned long long best = 0ull;
                #pragma unroll
                for (int j = 0; j < 4; ++j) {
                    int n = bn + j * 32 + col;
                    if (n < bRows) {
                        float v = acc[i][j][reg] + bias[n];
                        unsigned int u   = __float_as_uint(v);
                        unsigned int key = (u & 0x80000000u) ? ~u : (u | 0x80000000u);
                        unsigned long long pk =
                            ((unsigned long long)key << 32) |
                            (unsigned long long)(0xFFFFFFFFu - (unsigned)n);
                        best = (pk > best) ? pk : best;
                    }
                }
                #pragma unroll
                for (int sdist = 1; sdist < 32; sdist <<= 1) {
                    unsigned long long o = __shfl_xor(best, sdist, 64);
                    best = (o > best) ? o : best;
                }
                if (col == 0) atomicMax(&packed[m], best);
            }
}

// ---------------------------------------------------------------------------
// feats reduce: sum 8 split-K partials + bias, relu, split -> imgv blocked
// ---------------------------------------------------------------------------
__global__ void feats_reduce8(const float* __restrict__ part, const float* __restrict__ bias,
                              unsigned short* __restrict__ hi, unsigned short* __restrict__ lo) {
    int idx = blockIdx.x * 256 + threadIdx.x;   // 1024*64
    int b = idx >> 6, kc = idx & 63;
    int n = kc << 3;
    float v[8];
    #pragma unroll
    for (int e = 0; e < 8; ++e) v[e] = bias[n + e];
    #pragma unroll
    for (int z = 0; z < 8; ++z) {
        const float* s = part + (size_t)z * 1024 * 512 + (size_t)b * 512 + n;
        #pragma unroll
        for (int e = 0; e < 8; ++e) v[e] += s[e];
    }
    us8 vh, vl;
    #pragma unroll
    for (int e = 0; e < 8; ++e) {
        bfpair q = split2v(fmaxf(v[e], 0.f));
        vh[e] = q.hi; vl[e] = q.lo;
    }
    size_t o = ((size_t)kc * 1024 + b) * 8;
    *(us8*)(hi + o) = vh;
    *(us8*)(lo + o) = vl;
}

// ---------------------------------------------------------------------------
// LSTM pointwise; h -> xh slabs kc=64+j8; emits out[b][t-1] then zeroes packed
// ---------------------------------------------------------------------------
template<bool PRIME>
__global__ void lstm_pw_blk(const float* __restrict__ g0, const float* __restrict__ g1,
                            const float* __restrict__ bsum, float* __restrict__ cbuf,
                            unsigned short* __restrict__ xh_hi, unsigned short* __restrict__ xh_lo,
                            unsigned long long* __restrict__ packed,
                            int* __restrict__ out, int t) {
    int idx = blockIdx.x * 256 + threadIdx.x;   // 1024*64
    int b = idx >> 6, j8 = idx & 63;
    int j = j8 << 3;
    const float* g = g0 + (size_t)b * NGATE;
    float v[4][8];
    #pragma unroll
    for (int gt = 0; gt < 4; ++gt) {
        const float* s = g + gt * 512 + j;
        const float* bs = bsum + gt * 512 + j;
        #pragma unroll
        for (int e = 0; e < 8; ++e) v[gt][e] = s[e] + bs[e];
    }
    if (!PRIME) {
        const float* h2 = g1 + (size_t)b * NGATE;
        #pragma unroll
        for (int gt = 0; gt < 4; ++gt) {
            const float* s = h2 + gt * 512 + j;
            #pragma unroll
            for (int e = 0; e < 8; ++e) v[gt][e] += s[e];
        }
    }
    float* cb = cbuf + (size_t)b * 512 + j;
    us8 vh, vl;
    #pragma unroll
    for (int e = 0; e < 8; ++e) {
        float si = 1.f / (1.f + expf(-v[0][e]));
        float sf = 1.f / (1.f + expf(-v[1][e]));
        float tg = tanhf(v[2][e]);
        float so = 1.f / (1.f + expf(-v[3][e]));
        float cn = PRIME ? (si * tg) : (sf * cb[e] + si * tg);
        cb[e] = cn;
        bfpair q = split2v(so * tanhf(cn));
        vh[e] = q.hi; vl[e] = q.lo;
    }
    size_t o = ((size_t)(64 + j8) * 1024 + b) * 8;
    *(us8*)(xh_hi + o) = vh;
    *(us8*)(xh_lo + o) = vl;
    if (j8 == 0) {
        if (!PRIME && t > 0) {
            unsigned long long p = packed[b];
            out[b * SEQLEN + (t - 1)] = (int)(0xFFFFFFFFu - (unsigned)(p & 0xFFFFFFFFull));
        }
        packed[b] = 0ull;
    }
}

// ---------------------------------------------------------------------------
// embedding gather + split into xh slabs kc=0..63 (word from packed / START)
// ---------------------------------------------------------------------------
template<int FIRST>
__global__ void gather_blk(const float* __restrict__ emb,
                           const unsigned long long* __restrict__ packed,
                           unsigned short* __restrict__ xh_hi, unsigned short* __restrict__ xh_lo) {
    int idx = blockIdx.x * 256 + threadIdx.x;   // 1024*64
    int b = idx >> 6, kc = idx & 63;
    int word = 1;
    if (!FIRST) {
        unsigned long long p = packed[b];
        word = (int)(0xFFFFFFFFu - (unsigned)(p & 0xFFFFFFFFull)) + 2;
    }
    us8 vh, vl; split8(emb + (size_t)word * 512 + (kc << 3), vh, vl);
    size_t o = ((size_t)kc * 1024 + b) * 8;
    *(us8*)(xh_hi + o) = vh;
    *(us8*)(xh_lo + o) = vl;
}

__global__ void final_out(const unsigned long long* __restrict__ packed, int* __restrict__ out) {
    int b = blockIdx.x * 256 + threadIdx.x;
    if (b < BATCH) {
        unsigned long long p = packed[b];
        out[b * SEQLEN + (SEQLEN - 1)] = (int)(0xFFFFFFFFu - (unsigned)(p & 0xFFFFFFFFull));
    }
}

extern "C" void kernel_launch(void* const* d_in, const int* in_sizes, int n_in,
                              void* d_out, int out_size, void* d_ws, size_t ws_size,
                              hipStream_t stream) {
    const float* img     = (const float*)d_in[0];
    const float* W_feats = (const float*)d_in[1];
    const float* b_feats = (const float*)d_in[2];
    const float* W_ih    = (const float*)d_in[3];
    const float* W_hh    = (const float*)d_in[4];
    const float* b_ih    = (const float*)d_in[5];
    const float* b_hh    = (const float*)d_in[6];
    const float* emb     = (const float*)d_in[7];
    const float* W_out   = (const float*)d_in[8];
    const float* b_out   = (const float*)d_in[9];
    int* out = (int*)d_out;

    const size_t WCAT_H = (size_t)128 * 2048 * 8;
    const size_t WOUT_H = (size_t)64 * NVOCAB * 8;
    const size_t XH_H   = (size_t)128 * 1024 * 8;
    const size_t IMGV_H = (size_t)64 * 1024 * 8;

    char* p = (char*)d_ws;
    unsigned short* wcat_hi = (unsigned short*)p;  p += WCAT_H * 2;
    unsigned short* wcat_lo = (unsigned short*)p;  p += WCAT_H * 2;
    unsigned short* wout_hi = (unsigned short*)p;  p += WOUT_H * 2;
    unsigned short* wout_lo = (unsigned short*)p;  p += WOUT_H * 2;
    unsigned short* xh_hi   = (unsigned short*)p;  p += XH_H * 2;
    unsigned short* xh_lo   = (unsigned short*)p;  p += XH_H * 2;
    unsigned short* imgv_hi = (unsigned short*)p;  p += IMGV_H * 2;
    unsigned short* imgv_lo = (unsigned short*)p;  p += IMGV_H * 2;
    float* cbuf             = (float*)p;           p += (size_t)1024 * 512 * 4;
    float* bsum             = (float*)p;           p += (size_t)NGATE * 4;
    unsigned long long* packed = (unsigned long long*)p;  p += (size_t)1024 * 8;
    float* gates0           = (float*)p;           p += (size_t)1024 * NGATE * 4;
    float* gates1           = (float*)p;           p += (size_t)1024 * NGATE * 4;
    // transient blocked feats inputs alias the not-yet-written wout region
    unsigned short* imgb_hi = wout_hi;
    unsigned short* imgb_lo = imgb_hi + (size_t)512 * 1024 * 8;
    unsigned short* wfb_hi  = imgb_lo + (size_t)512 * 1024 * 8;
    unsigned short* wfb_lo  = wfb_hi  + (size_t)512 * 512 * 8;
    float* partials = gates0;   // 8 x (1024x512) fp32 = gates0+gates1 region

    // ---- one-time prep
    prep_wcat_blk<<<1024, 256, 0, stream>>>(W_ih, W_hh, b_ih, b_hh, wcat_hi, wcat_lo, bsum);
    prep_blk<<<dim3(4, 512), 256, 0, stream>>>(img,     imgb_hi, imgb_lo, 1024, FEATS);
    prep_blk<<<dim3(2, 512), 256, 0, stream>>>(W_feats, wfb_hi,  wfb_lo,  512,  FEATS);

    // feats: partials[z] = img(chunk z) @ W_feats(chunk z)^T, split-K x8
    k_gemm_feats<<<dim3(4, 8, 8), 256, 0, stream>>>(imgb_hi, imgb_lo, wfb_hi, wfb_lo, partials);
    feats_reduce8<<<256, 256, 0, stream>>>(partials, b_feats, imgv_hi, imgv_lo);

    // feats transients dead -> build blocked W_out in place
    prep_blk<<<dim3(47, 64), 256, 0, stream>>>(W_out, wout_hi, wout_lo, NVOCAB, 512);

    // prime LSTM: gates0 = imgv @ W_ih^T (Wcat kc 0..63)
    k_gemm_gates<<<dim3(16, 8, 1), 256, 0, stream>>>(imgv_hi, imgv_lo, wcat_hi, wcat_lo,
                                                     gates0, 0, 0, 0);
    lstm_pw_blk<true><<<256, 256, 0, stream>>>(gates0, nullptr, bsum, cbuf,
                                               xh_hi, xh_lo, packed, out, 0);

    for (int t = 0; t < SEQLEN; ++t) {
        if (t == 0) gather_blk<1><<<256, 256, 0, stream>>>(emb, packed, xh_hi, xh_lo);
        else        gather_blk<0><<<256, 256, 0, stream>>>(emb, packed, xh_hi, xh_lo);
        // gates{0,1} = xh(kc chunk z) @ Wcat(kc chunk z)^T, split-K x2
        k_gemm_gates<<<dim3(16, 8, 2), 256, 0, stream>>>(
            xh_hi, xh_lo, wcat_hi, wcat_lo, gates0,
            (size_t)64 * 1024 * 8, (size_t)64 * 2048 * 8, (size_t)1024 * NGATE);
        lstm_pw_blk<false><<<256, 256, 0, stream>>>(gates0, gates1, bsum, cbuf,
                                                    xh_hi, xh_lo, packed, out, t);
        // logits = h @ W_out^T + b_out, fused argmax (A = h slabs kc 64..127)
        k_logits_argmax<<<dim3(94, 8), 128, 0, stream>>>(
            xh_hi + (size_t)64 * 1024 * 8, xh_lo + (size_t)64 * 1024 * 8,
            wout_hi, wout_lo, b_out, packed);
    }
    final_out<<<4, 256, 0, stream>>>(packed, out);
}